// Round 8
// baseline (300.522 us; speedup 1.0000x reference)
//
#include <hip/hip_runtime.h>
#include <math.h>

#define NF 256
#define NH 128
#define NC 16
#define NPART 8
#define NCHUNK 128
#define CAP 128

typedef __attribute__((ext_vector_type(8))) short bf16x8;
typedef __attribute__((ext_vector_type(4))) float f32x4;

// ---- bf16 helpers ---------------------------------------------------------
__device__ __forceinline__ unsigned f2b(float f) {            // RNE to bf16 bits
    unsigned u = __float_as_uint(f);
    return (u + 0x7FFFu + ((u >> 16) & 1u)) >> 16;
}
__device__ __forceinline__ unsigned pack2(float a, float b) { // RNE pair
    return f2b(a) | (f2b(b) << 16);
}
__device__ __forceinline__ unsigned packt(float a, float b) { // truncate pair (MFMA inputs)
    return (__float_as_uint(a) >> 16) | (__float_as_uint(b) & 0xFFFF0000u);
}
__device__ __forceinline__ float blo(unsigned u) { return __uint_as_float(u << 16); }
__device__ __forceinline__ float bhi(unsigned u) { return __uint_as_float(u & 0xFFFF0000u); }

// ---------------------------------------------------------------------------
// Bucket-CSR build in ONE pass: colidx2d[d][pos]=src, cnt[d]=degree.
// XCD-locality GUARANTEED: each block reads its hardware XCD id
// (s_getreg HW_REG_XCC_ID=20 [m09]) and serves the matching node-partition
// via per-partition chunk-stealing counters; steals other partitions only
// after its own drains (correctness independent of the XCD read: all
// NPART*NCHUNK (part,chunk) pairs are claimed exactly once by someone).
// Partition working set = cnt 25KB + colidx2d 3.2MB -> one XCD's 4MB L2.
__global__ void fillbucket_kernel(const int* __restrict__ src, const int* __restrict__ dst,
                                  int* __restrict__ cnt, unsigned short* __restrict__ colidx2d,
                                  int* __restrict__ ctr, int E, int N) {
    __shared__ int schunk;
    unsigned mypart = (unsigned)__builtin_amdgcn_s_getreg((3 << 11) | 20) & 7u; // id20,off0,sz4
    int psz = (N + NPART - 1) / NPART;
    for (int pass = 0; pass < NPART; ++pass) {
        int part = (int)((mypart + pass) & 7u);
        int lo = part * psz;
        int hi = lo + psz; if (hi > N) hi = N;
        for (;;) {
            if (threadIdx.x == 0) schunk = atomicAdd(&ctr[part], 1);
            __syncthreads();
            int chunk = schunk;
            __syncthreads();
            if (chunk >= NCHUNK) break;
            int e0 = (int)((long long)chunk * E / NCHUNK);
            int e1 = (int)((long long)(chunk + 1) * E / NCHUNK);
            for (int e = e0 + (int)threadIdx.x; e < e1; e += 256) {
                int d = dst[e];
                if (d >= lo && d < hi) {
                    int pos = atomicAdd(&cnt[d], 1);
                    if (pos < CAP) colidx2d[(size_t)d * CAP + pos] = (unsigned short)src[e];
                }
            }
        }
    }
}

// ---------------------------------------------------------------------------
__global__ void dis_kernel(const int* __restrict__ cnt, float* __restrict__ dis, int N) {
    int i = blockIdx.x * 256 + threadIdx.x;
    if (i < N) dis[i] = rsqrtf((float)(cnt[i] + 1));
}

// ---------------------------------------------------------------------------
// h1 = dis * (x @ W1) via MFMA bf16, stored bf16 (ushort row-major [N][128]).
// W1 staged once/block into LDS bf16-transposed [n=128][k=256] (64KB) with
// XOR swizzle byte^=(n&7)<<4. 64 rows/block, 4 waves x 16 rows.
__global__ __launch_bounds__(256) void gemm1_mfma_kernel(
    const float* __restrict__ x, const float* __restrict__ W1,
    const float* __restrict__ dis, unsigned short* __restrict__ h1us, int N) {
    __shared__ char sW1T[65536];
    int tid = threadIdx.x;
    for (int idx = tid; idx < NF * NH; idx += 256) {
        int k = idx >> 7, n = idx & 127;
        unsigned short h = (unsigned short)f2b(W1[idx]);
        *(unsigned short*)(sW1T + n * 512 + ((k * 2) ^ ((n & 7) << 4))) = h;
    }
    __syncthreads();

    int wid = tid >> 6, lane = tid & 63;
    int lrow = lane & 15, lk = lane >> 4;      // A-frag: row=lane&15, k-chunk=lane>>4
    int rb = blockIdx.x * 64 + wid * 16;
    int ra = rb + lrow;
    int rc = ra < N ? ra : N - 1;              // clamp (last block); extras discarded
    const float* xr = x + (size_t)rc * NF + lk * 8;

    f32x4 acc[8];
#pragma unroll
    for (int t = 0; t < 8; ++t) acc[t] = (f32x4){0.f, 0.f, 0.f, 0.f};

#pragma unroll
    for (int kk = 0; kk < 8; ++kk) {
        float4 lo = *reinterpret_cast<const float4*>(xr + kk * 32);
        float4 hi = *reinterpret_cast<const float4*>(xr + kk * 32 + 4);
        union { unsigned u[4]; bf16x8 v; } av;
        av.u[0] = packt(lo.x, lo.y);
        av.u[1] = packt(lo.z, lo.w);
        av.u[2] = packt(hi.x, hi.y);
        av.u[3] = packt(hi.z, hi.w);
        int kbyte = kk * 64 + lk * 16;
#pragma unroll
        for (int nt = 0; nt < 8; ++nt) {
            int n = nt * 16 + lrow;            // B-frag: col=lane&15, k-chunk=lane>>4
            bf16x8 bv = *(const bf16x8*)(sW1T + n * 512 + (kbyte ^ ((n & 7) << 4)));
            acc[nt] = __builtin_amdgcn_mfma_f32_16x16x32_bf16(av.v, bv, acc[nt], 0, 0, 0);
        }
    }
    // C/D layout (verified m89): col = lane&15, row_in_tile = (lane>>4)*4 + r
    int crow0 = rb + lk * 4;
#pragma unroll
    for (int r = 0; r < 4; ++r) {
        int row = crow0 + r;
        if (row < N) {
            float dr = dis[row];
            unsigned short* orow = h1us + (size_t)row * NH + lrow;
#pragma unroll
            for (int nt = 0; nt < 8; ++nt)
                orow[nt * 16] = (unsigned short)f2b(acc[nt][r] * dr);
        }
    }
}

// ---------------------------------------------------------------------------
// Layer 1 pull + ReLU + GEMM2, fused.  One wave per node (4 nodes/block).
__global__ __launch_bounds__(256) void layer1_kernel(
    const int* __restrict__ cnt, const unsigned short* __restrict__ colidx2d,
    const unsigned* __restrict__ h1sb, const float* __restrict__ dis,
    const float* __restrict__ b1, const float* __restrict__ W2,
    unsigned* __restrict__ h2sb, int N) {
    __shared__ float sW2[NH * NC];   // 8 KB
    __shared__ float srow[4][NH];    // 2 KB
    int tid = threadIdx.x;
    for (int k = tid; k < NH * NC; k += 256) sW2[k] = W2[k];
    __syncthreads();

    int wid = tid >> 6, lane = tid & 63;
    int i = blockIdx.x * 4 + wid;
    if (i >= N) return;
    int cn = cnt[i]; if (cn > CAP) cn = CAP;
    const unsigned short* ci = colidx2d + (size_t)i * CAP;
    unsigned sv = h1sb[(size_t)i * 64 + lane];          // self-loop
    float accx = blo(sv), accy = bhi(sv);
    int k = 0;
    for (; k + 4 <= cn; k += 4) {
        int a = ci[k], b = ci[k + 1], c = ci[k + 2], d = ci[k + 3];
        unsigned va = h1sb[(size_t)a * 64 + lane];
        unsigned vb = h1sb[(size_t)b * 64 + lane];
        unsigned vc = h1sb[(size_t)c * 64 + lane];
        unsigned vd = h1sb[(size_t)d * 64 + lane];
        accx += (blo(va) + blo(vb)) + (blo(vc) + blo(vd));
        accy += (bhi(va) + bhi(vb)) + (bhi(vc) + bhi(vd));
    }
    for (; k < cn; ++k) {
        unsigned v = h1sb[(size_t)ci[k] * 64 + lane];
        accx += blo(v); accy += bhi(v);
    }
    float di = dis[i];
    int c0 = lane * 2;
    srow[wid][c0]     = fmaxf(di * accx + b1[c0], 0.f);
    srow[wid][c0 + 1] = fmaxf(di * accy + b1[c0 + 1], 0.f);
    int j = lane & 15, q = lane >> 4;
    const float* rw = srow[wid];
    float p = 0.f;
#pragma unroll
    for (int cc = 0; cc < 32; ++cc) {
        int c = q * 32 + cc;
        p += rw[c] * sW2[c * NC + j];
    }
    p += __shfl_xor(p, 16, 64);
    p += __shfl_xor(p, 32, 64);
    float dp = di * p;
    float plo = __shfl(dp, (lane << 1) & 63, 64);
    float phi = __shfl(dp, ((lane << 1) | 1) & 63, 64);
    if (lane < 8) h2sb[(size_t)i * 8 + lane] = pack2(plo, phi);
}

// ---------------------------------------------------------------------------
// Layer 2 pull + bias + log_softmax.  8 lanes/node (2 classes per lane).
__global__ void layer2_kernel(const int* __restrict__ cnt, const unsigned short* __restrict__ colidx2d,
                              const unsigned* __restrict__ h2sb, const float* __restrict__ dis,
                              const float* __restrict__ b2, float* __restrict__ out, int N) {
    int t = blockIdx.x * 256 + threadIdx.x;
    int i = t >> 3;
    if (i >= N) return;
    int j2 = t & 7;
    int cn = cnt[i]; if (cn > CAP) cn = CAP;
    const unsigned short* ci = colidx2d + (size_t)i * CAP;
    unsigned sv = h2sb[(size_t)i * 8 + j2];             // self-loop
    float ax = blo(sv), ay = bhi(sv);
    int k = 0;
    for (; k + 4 <= cn; k += 4) {
        int a = ci[k], b = ci[k + 1], c = ci[k + 2], d = ci[k + 3];
        unsigned ga = h2sb[(size_t)a * 8 + j2];
        unsigned gb = h2sb[(size_t)b * 8 + j2];
        unsigned gc = h2sb[(size_t)c * 8 + j2];
        unsigned gd = h2sb[(size_t)d * 8 + j2];
        ax += (blo(ga) + blo(gb)) + (blo(gc) + blo(gd));
        ay += (bhi(ga) + bhi(gb)) + (bhi(gc) + bhi(gd));
    }
    for (; k < cn; ++k) {
        unsigned g = h2sb[(size_t)ci[k] * 8 + j2];
        ax += blo(g); ay += bhi(g);
    }
    float di = dis[i];
    float l0 = di * ax + b2[2 * j2];
    float l1 = di * ay + b2[2 * j2 + 1];
    float m = fmaxf(l0, l1);
    m = fmaxf(m, __shfl_xor(m, 1, 64));
    m = fmaxf(m, __shfl_xor(m, 2, 64));
    m = fmaxf(m, __shfl_xor(m, 4, 64));
    float s = __expf(l0 - m) + __expf(l1 - m);
    s += __shfl_xor(s, 1, 64);
    s += __shfl_xor(s, 2, 64);
    s += __shfl_xor(s, 4, 64);
    float lse = m + __logf(s);
    float2 o = make_float2(l0 - lse, l1 - lse);
    *reinterpret_cast<float2*>(out + (size_t)i * NC + 2 * j2) = o;
}

// ---------------------------------------------------------------------------
extern "C" void kernel_launch(void* const* d_in, const int* in_sizes, int n_in,
                              void* d_out, int out_size, void* d_ws, size_t ws_size,
                              hipStream_t stream) {
    const float* x  = (const float*)d_in[0];
    const int*   ei = (const int*)d_in[1];
    const float* W1 = (const float*)d_in[2];
    const float* b1 = (const float*)d_in[3];
    const float* W2 = (const float*)d_in[4];
    const float* b2 = (const float*)d_in[5];
    float* out = (float*)d_out;

    const int N = in_sizes[0] / NF;   // 50000
    const int E = in_sizes[1] / 2;    // 1600000
    const int* src = ei;
    const int* dst = ei + E;

    // workspace layout (~27.6 MB)
    unsigned*       h1sb     = (unsigned*)d_ws;                 // N*64 u32 (12.8 MB)
    unsigned*       h2sb     = h1sb + (size_t)N * 64;           // N*8  u32 (1.6 MB)
    float*          dis      = (float*)(h2sb + (size_t)N * 8);  // N
    int*            cnt      = (int*)(dis + N);                 // N
    int*            ctr      = cnt + N;                         // 64 (8 used)
    unsigned short* colidx2d = (unsigned short*)(ctr + 64);     // N*CAP u16 (12.8 MB)

    hipMemsetAsync(cnt, 0, (size_t)(N + 64) * sizeof(int), stream);  // cnt + ctr

    fillbucket_kernel<<<1024, 256, 0, stream>>>(src, dst, cnt, colidx2d, ctr, E, N);

    dis_kernel<<<(N + 255) / 256, 256, 0, stream>>>(cnt, dis, N);

    gemm1_mfma_kernel<<<(N + 63) / 64, 256, 0, stream>>>(x, W1, dis,
                                                         (unsigned short*)h1sb, N);

    layer1_kernel<<<(N + 3) / 4, 256, 0, stream>>>(cnt, colidx2d, h1sb, dis, b1, W2, h2sb, N);

    layer2_kernel<<<((size_t)N * 8 + 255) / 256, 256, 0, stream>>>(cnt, colidx2d, h2sb, dis, b2, out, N);
}

// Round 9
// 187.040 us; speedup vs baseline: 1.6067x; 1.6067x over previous
//
#include <hip/hip_runtime.h>
#include <math.h>

#define NF 256
#define NH 128
#define NC 16
#define NB 391      // buckets of 128 nodes: 391*128 = 50048 >= 50000
#define NBLK 128    // binning blocks (must equal passA/passB grid)

typedef __attribute__((ext_vector_type(8))) short bf16x8;
typedef __attribute__((ext_vector_type(4))) float f32x4;

// ---- bf16 helpers ---------------------------------------------------------
__device__ __forceinline__ unsigned f2b(float f) {            // RNE to bf16 bits
    unsigned u = __float_as_uint(f);
    return (u + 0x7FFFu + ((u >> 16) & 1u)) >> 16;
}
__device__ __forceinline__ unsigned pack2(float a, float b) { // RNE pair
    return f2b(a) | (f2b(b) << 16);
}
__device__ __forceinline__ unsigned packt(float a, float b) { // truncate pair (MFMA inputs)
    return (__float_as_uint(a) >> 16) | (__float_as_uint(b) & 0xFFFF0000u);
}
__device__ __forceinline__ float blo(unsigned u) { return __uint_as_float(u << 16); }
__device__ __forceinline__ float bhi(unsigned u) { return __uint_as_float(u & 0xFFFF0000u); }

// ---------------------------------------------------------------------------
// passA: per-block bucket histogram (LDS atomics only; coalesced row write).
__global__ void passA_kernel(const int* __restrict__ dst, int* __restrict__ hist, int E) {
    __shared__ int h[NB];
    for (int i = threadIdx.x; i < NB; i += 256) h[i] = 0;
    __syncthreads();
    int b = blockIdx.x;
    int e0 = (int)((long long)b * E / NBLK), e1 = (int)((long long)(b + 1) * E / NBLK);
    for (int e = e0 + (int)threadIdx.x; e < e1; e += 256)
        atomicAdd(&h[dst[e] >> 7], 1);
    __syncthreads();
    for (int i = threadIdx.x; i < NB; i += 256) hist[b * NB + i] = h[i];
}

// scanR: bucketsum[k] = sum over blocks of hist[b][k].
__global__ void scanR_kernel(const int* __restrict__ hist, int* __restrict__ bsum) {
    __shared__ int sm[NBLK];
    int k = blockIdx.x, t = threadIdx.x;
    sm[t] = hist[t * NB + k];
    __syncthreads();
    for (int off = NBLK / 2; off > 0; off >>= 1) {
        if (t < off) sm[t] += sm[t + off];
        __syncthreads();
    }
    if (t == 0) bsum[k] = sm[0];
}

// scanB: exclusive scan of NB bucket sums -> bbase[NB+1]; rowptr[N]=E.
__global__ void scanB_kernel(const int* __restrict__ bsum, int* __restrict__ bbase,
                             int* __restrict__ rowptr, int N, int E) {
    __shared__ int sm[512];
    int t = threadIdx.x;
    int v = (t < NB) ? bsum[t] : 0;
    sm[t] = v;
    __syncthreads();
    for (int off = 1; off < 512; off <<= 1) {
        int u = (t >= off) ? sm[t - off] : 0;
        __syncthreads();
        sm[t] += u;
        __syncthreads();
    }
    if (t < NB) bbase[t] = sm[t] - v;
    if (t == 0) { bbase[NB] = E; rowptr[N] = E; }
}

// scanC: per-bucket column exclusive scan across blocks + bucket base
// (overwrites hist with each block's exact output offset for that bucket).
__global__ void scanC_kernel(int* __restrict__ hist, const int* __restrict__ bbase) {
    __shared__ int sm[NBLK];
    int k = blockIdx.x, t = threadIdx.x;
    int v = hist[t * NB + k];
    sm[t] = v;
    __syncthreads();
    for (int off = 1; off < NBLK; off <<= 1) {
        int u = (t >= off) ? sm[t - off] : 0;
        __syncthreads();
        sm[t] += u;
        __syncthreads();
    }
    hist[t * NB + k] = bbase[k] + sm[t] - v;
}

// passB: binned scatter to bucket-sorted edge words. LDS cursors hold GLOBAL
// slots (disjoint per block, exact) -> no global atomics, deterministic
// ranges, writes land in ~32-entry contiguous runs (lines fill fully).
__global__ void passB_kernel(const int* __restrict__ src, const int* __restrict__ dst,
                             const int* __restrict__ hist, unsigned* __restrict__ ebuf,
                             int E) {
    __shared__ int cur[NB];
    int b = blockIdx.x;
    for (int i = threadIdx.x; i < NB; i += 256) cur[i] = hist[b * NB + i];
    __syncthreads();
    int e0 = (int)((long long)b * E / NBLK), e1 = (int)((long long)(b + 1) * E / NBLK);
    for (int e = e0 + (int)threadIdx.x; e < e1; e += 256) {
        int d = dst[e];
        int pos = atomicAdd(&cur[d >> 7], 1);
        ebuf[pos] = ((unsigned)d << 16) | (unsigned)src[e];
    }
}

// passC: one block per bucket: per-node histogram -> rowptr/dis, then in-bucket
// scatter to final dst-sorted u16 colidx (8KB window, L2-hot).
__global__ void passC_kernel(const unsigned* __restrict__ ebuf, const int* __restrict__ bbase,
                             int* __restrict__ rowptr, float* __restrict__ dis,
                             unsigned short* __restrict__ colidx, int N) {
    __shared__ int h[128];
    __shared__ int s2[128];
    __shared__ int curp[128];
    int k = blockIdx.x, t = threadIdx.x;
    if (t < 128) h[t] = 0;
    __syncthreads();
    int e0 = bbase[k], e1 = bbase[k + 1];
    for (int e = e0 + t; e < e1; e += 256)
        atomicAdd(&h[(ebuf[e] >> 16) & 127], 1);
    __syncthreads();
    int v = (t < 128) ? h[t] : 0;
    if (t < 128) s2[t] = v;
    __syncthreads();
    for (int off = 1; off < 128; off <<= 1) {
        int u = (t < 128 && t >= off) ? s2[t - off] : 0;
        __syncthreads();
        if (t < 128) s2[t] += u;
        __syncthreads();
    }
    if (t < 128) {
        int node = k * 128 + t;
        int r = e0 + s2[t] - v;             // exclusive prefix -> first slot of node
        if (node < N) {
            rowptr[node] = r;
            dis[node] = rsqrtf((float)(v + 1));
        }
        curp[t] = r;
    }
    __syncthreads();
    for (int e = e0 + t; e < e1; e += 256) {
        unsigned w = ebuf[e];
        int dl = (w >> 16) & 127;
        int pos = atomicAdd(&curp[dl], 1);
        colidx[pos] = (unsigned short)(w & 0xFFFFu);
    }
}

// ---------------------------------------------------------------------------
// h1 = dis * (x @ W1) via MFMA bf16, stored bf16 (ushort row-major [N][128]).
// W1 staged once/block into LDS bf16-transposed [n=128][k=256] (64KB) with
// XOR swizzle byte^=(n&7)<<4. 64 rows/block, 4 waves x 16 rows.
__global__ __launch_bounds__(256) void gemm1_mfma_kernel(
    const float* __restrict__ x, const float* __restrict__ W1,
    const float* __restrict__ dis, unsigned short* __restrict__ h1us, int N) {
    __shared__ char sW1T[65536];
    int tid = threadIdx.x;
    for (int idx = tid; idx < NF * NH; idx += 256) {
        int k = idx >> 7, n = idx & 127;
        unsigned short h = (unsigned short)f2b(W1[idx]);
        *(unsigned short*)(sW1T + n * 512 + ((k * 2) ^ ((n & 7) << 4))) = h;
    }
    __syncthreads();

    int wid = tid >> 6, lane = tid & 63;
    int lrow = lane & 15, lk = lane >> 4;      // A-frag: row=lane&15, k-chunk=lane>>4
    int rb = blockIdx.x * 64 + wid * 16;
    int ra = rb + lrow;
    int rc = ra < N ? ra : N - 1;              // clamp (last block); extras discarded
    const float* xr = x + (size_t)rc * NF + lk * 8;

    f32x4 acc[8];
#pragma unroll
    for (int t = 0; t < 8; ++t) acc[t] = (f32x4){0.f, 0.f, 0.f, 0.f};

#pragma unroll
    for (int kk = 0; kk < 8; ++kk) {
        float4 lo = *reinterpret_cast<const float4*>(xr + kk * 32);
        float4 hi = *reinterpret_cast<const float4*>(xr + kk * 32 + 4);
        union { unsigned u[4]; bf16x8 v; } av;
        av.u[0] = packt(lo.x, lo.y);
        av.u[1] = packt(lo.z, lo.w);
        av.u[2] = packt(hi.x, hi.y);
        av.u[3] = packt(hi.z, hi.w);
        int kbyte = kk * 64 + lk * 16;
#pragma unroll
        for (int nt = 0; nt < 8; ++nt) {
            int n = nt * 16 + lrow;            // B-frag: col=lane&15, k-chunk=lane>>4
            bf16x8 bv = *(const bf16x8*)(sW1T + n * 512 + (kbyte ^ ((n & 7) << 4)));
            acc[nt] = __builtin_amdgcn_mfma_f32_16x16x32_bf16(av.v, bv, acc[nt], 0, 0, 0);
        }
    }
    // C/D layout (verified m89): col = lane&15, row_in_tile = (lane>>4)*4 + r
    int crow0 = rb + lk * 4;
#pragma unroll
    for (int r = 0; r < 4; ++r) {
        int row = crow0 + r;
        if (row < N) {
            float dr = dis[row];
            unsigned short* orow = h1us + (size_t)row * NH + lrow;
#pragma unroll
            for (int nt = 0; nt < 8; ++nt)
                orow[nt * 16] = (unsigned short)f2b(acc[nt][r] * dr);
        }
    }
}

// ---------------------------------------------------------------------------
// Layer 1 pull + ReLU + GEMM2, fused.  One wave per node (4 nodes/block).
__global__ __launch_bounds__(256) void layer1_kernel(
    const int* __restrict__ rowptr, const unsigned short* __restrict__ colidx,
    const unsigned* __restrict__ h1sb, const float* __restrict__ dis,
    const float* __restrict__ b1, const float* __restrict__ W2,
    unsigned* __restrict__ h2sb, int N) {
    __shared__ float sW2[NH * NC];   // 8 KB
    __shared__ float srow[4][NH];    // 2 KB
    int tid = threadIdx.x;
    for (int k = tid; k < NH * NC; k += 256) sW2[k] = W2[k];
    __syncthreads();

    int wid = tid >> 6, lane = tid & 63;
    int i = blockIdx.x * 4 + wid;
    if (i >= N) return;
    int e = rowptr[i], e1 = rowptr[i + 1];
    unsigned sv = h1sb[(size_t)i * 64 + lane];          // self-loop
    float accx = blo(sv), accy = bhi(sv);
    for (; e + 4 <= e1; e += 4) {
        int a = colidx[e], b = colidx[e + 1], c = colidx[e + 2], d = colidx[e + 3];
        unsigned va = h1sb[(size_t)a * 64 + lane];
        unsigned vb = h1sb[(size_t)b * 64 + lane];
        unsigned vc = h1sb[(size_t)c * 64 + lane];
        unsigned vd = h1sb[(size_t)d * 64 + lane];
        accx += (blo(va) + blo(vb)) + (blo(vc) + blo(vd));
        accy += (bhi(va) + bhi(vb)) + (bhi(vc) + bhi(vd));
    }
    for (; e < e1; ++e) {
        unsigned v = h1sb[(size_t)colidx[e] * 64 + lane];
        accx += blo(v); accy += bhi(v);
    }
    float di = dis[i];
    int c0 = lane * 2;
    srow[wid][c0]     = fmaxf(di * accx + b1[c0], 0.f);
    srow[wid][c0 + 1] = fmaxf(di * accy + b1[c0 + 1], 0.f);
    int j = lane & 15, q = lane >> 4;
    const float* rw = srow[wid];
    float p = 0.f;
#pragma unroll
    for (int cc = 0; cc < 32; ++cc) {
        int c = q * 32 + cc;
        p += rw[c] * sW2[c * NC + j];
    }
    p += __shfl_xor(p, 16, 64);
    p += __shfl_xor(p, 32, 64);
    float dp = di * p;
    float plo = __shfl(dp, (lane << 1) & 63, 64);
    float phi = __shfl(dp, ((lane << 1) | 1) & 63, 64);
    if (lane < 8) h2sb[(size_t)i * 8 + lane] = pack2(plo, phi);
}

// ---------------------------------------------------------------------------
// Layer 2 pull + bias + log_softmax.  8 lanes/node (2 classes per lane).
__global__ void layer2_kernel(const int* __restrict__ rowptr, const unsigned short* __restrict__ colidx,
                              const unsigned* __restrict__ h2sb, const float* __restrict__ dis,
                              const float* __restrict__ b2, float* __restrict__ out, int N) {
    int t = blockIdx.x * 256 + threadIdx.x;
    int i = t >> 3;
    if (i >= N) return;
    int j2 = t & 7;
    int e = rowptr[i], e1 = rowptr[i + 1];
    unsigned sv = h2sb[(size_t)i * 8 + j2];             // self-loop
    float ax = blo(sv), ay = bhi(sv);
    for (; e + 4 <= e1; e += 4) {
        int a = colidx[e], b = colidx[e + 1], c = colidx[e + 2], d = colidx[e + 3];
        unsigned ga = h2sb[(size_t)a * 8 + j2];
        unsigned gb = h2sb[(size_t)b * 8 + j2];
        unsigned gc = h2sb[(size_t)c * 8 + j2];
        unsigned gd = h2sb[(size_t)d * 8 + j2];
        ax += (blo(ga) + blo(gb)) + (blo(gc) + blo(gd));
        ay += (bhi(ga) + bhi(gb)) + (bhi(gc) + bhi(gd));
    }
    for (; e < e1; ++e) {
        unsigned g = h2sb[(size_t)colidx[e] * 8 + j2];
        ax += blo(g); ay += bhi(g);
    }
    float di = dis[i];
    float l0 = di * ax + b2[2 * j2];
    float l1 = di * ay + b2[2 * j2 + 1];
    float m = fmaxf(l0, l1);
    m = fmaxf(m, __shfl_xor(m, 1, 64));
    m = fmaxf(m, __shfl_xor(m, 2, 64));
    m = fmaxf(m, __shfl_xor(m, 4, 64));
    float s = __expf(l0 - m) + __expf(l1 - m);
    s += __shfl_xor(s, 1, 64);
    s += __shfl_xor(s, 2, 64);
    s += __shfl_xor(s, 4, 64);
    float lse = m + __logf(s);
    float2 o = make_float2(l0 - lse, l1 - lse);
    *reinterpret_cast<float2*>(out + (size_t)i * NC + 2 * j2) = o;
}

// ---------------------------------------------------------------------------
extern "C" void kernel_launch(void* const* d_in, const int* in_sizes, int n_in,
                              void* d_out, int out_size, void* d_ws, size_t ws_size,
                              hipStream_t stream) {
    const float* x  = (const float*)d_in[0];
    const int*   ei = (const int*)d_in[1];
    const float* W1 = (const float*)d_in[2];
    const float* b1 = (const float*)d_in[3];
    const float* W2 = (const float*)d_in[4];
    const float* b2 = (const float*)d_in[5];
    float* out = (float*)d_out;

    const int N = in_sizes[0] / NF;   // 50000
    const int E = in_sizes[1] / 2;    // 1600000
    const int* src = ei;
    const int* dst = ei + E;

    // workspace layout (~25 MB); every consumed cell rewritten per call -> no memsets
    unsigned*       h1sb   = (unsigned*)d_ws;                  // N*64 u32 (12.8 MB)
    unsigned*       h2sb   = h1sb + (size_t)N * 64;            // N*8  u32 (1.6 MB)
    float*          dis    = (float*)(h2sb + (size_t)N * 8);   // N
    int*            rowptr = (int*)(dis + N);                  // N+1
    int*            hist   = rowptr + N + 1;                   // NBLK*NB (200 KB)
    int*            bsum   = hist + NBLK * NB;                 // NB
    int*            bbase  = bsum + NB;                        // NB+1
    unsigned*       ebuf   = (unsigned*)(bbase + NB + 1);      // E u32 (6.4 MB)
    unsigned short* colidx = (unsigned short*)(ebuf + E);      // E u16 (3.2 MB)

    passA_kernel<<<NBLK, 256, 0, stream>>>(dst, hist, E);
    scanR_kernel<<<NB, NBLK, 0, stream>>>(hist, bsum);
    scanB_kernel<<<1, 512, 0, stream>>>(bsum, bbase, rowptr, N, E);
    scanC_kernel<<<NB, NBLK, 0, stream>>>(hist, bbase);
    passB_kernel<<<NBLK, 256, 0, stream>>>(src, dst, hist, ebuf, E);
    passC_kernel<<<NB, 256, 0, stream>>>(ebuf, bbase, rowptr, dis, colidx, N);

    gemm1_mfma_kernel<<<(N + 63) / 64, 256, 0, stream>>>(x, W1, dis,
                                                         (unsigned short*)h1sb, N);

    layer1_kernel<<<(N + 3) / 4, 256, 0, stream>>>(rowptr, colidx, h1sb, dis, b1, W2, h2sb, N);

    layer2_kernel<<<((size_t)N * 8 + 255) / 256, 256, 0, stream>>>(rowptr, colidx, h2sb, dis, b2, out, N);
}